// Round 2
// baseline (426.889 us; speedup 1.0000x reference)
//
#include <hip/hip_runtime.h>

// NMS 3x3, replicate pad, strict >, running max initialized at 0.
// x: (8, 32, 512, 512) fp32. out = x * (x > max(0, 8 neighbors)).
//
// Register-rolling separable stencil, no LDS. Each thread owns a float4
// column group (4 cols) x RPT=8 rows. Per input row r it loads the aligned
// float4 plus 2 clamped halo scalars (L1 hits off neighbors' lines), and
// folds them to h2 = max(left,right) and h3 = max(h2, center). Output row r
// then needs only m8 = max(h3[r-1], h2[r], h3[r+1]) -> 4 fmax/pixel and
// 1.25x read amplification (10 rows loaded per 8 computed). Clamped
// row/col indices reproduce replicate padding exactly: a border pixel's
// clamped neighbor equals itself, so strict > fails there -> 0, matching
// the reference.

#define IMG_W 512
#define IMG_H 512
#define RPT 8       // rows per thread
#define THREADS 256 // 128 col-groups x 2 row-halves -> block tile 512x16

__device__ __forceinline__ float4 vmax4(float4 a, float4 b) {
    return make_float4(fmaxf(a.x, b.x), fmaxf(a.y, b.y),
                       fmaxf(a.z, b.z), fmaxf(a.w, b.w));
}

__global__ __launch_bounds__(THREADS)
void nms3x3_kernel(const float* __restrict__ x, float* __restrict__ out) {
    const int cg   = threadIdx.x & 127;   // col-group within row
    const int half = threadIdx.x >> 7;    // which 8-row half of the tile
    const int c0   = cg << 2;
    const int r0   = blockIdx.x * (2 * RPT) + half * RPT;
    const size_t plane = (size_t)blockIdx.y * IMG_H * IMG_W;
    const float* img  = x + plane;
    float*       oimg = out + plane;

    const int cl = (c0 == 0) ? 0 : c0 - 1;                    // left halo col
    const int cr = (c0 + 4 >= IMG_W) ? IMG_W - 1 : c0 + 4;    // right halo col

    auto loadrow = [&](int r, float4& h3o, float4& h2o, float4& vo) {
        r = min(IMG_H - 1, max(0, r));
        const float* rowp = img + (size_t)r * IMG_W;
        const float4 v  = *(const float4*)(rowp + c0);
        const float  sL = rowp[cl];
        const float  sR = rowp[cr];
        const float4 l  = make_float4(sL, v.x, v.y, v.z);
        const float4 rr = make_float4(v.y, v.z, v.w, sR);
        h2o = vmax4(l, rr);        // horizontal 2-max (center excluded)
        h3o = vmax4(h2o, v);       // horizontal 3-max
        vo  = v;
    };

    float4 h3p, h2p, vp, h3c, h2c, vc, h3n, h2n, vn;
    loadrow(r0 - 1, h3p, h2p, vp);
    loadrow(r0,     h3c, h2c, vc);

#pragma unroll
    for (int k = 0; k < RPT; ++k) {
        loadrow(r0 + k + 1, h3n, h2n, vn);
        // max over 8 neighbors; running max starts at 0 (center tap zeroed),
        // but inputs can be negative and 0 > negative m8 only flips the mask
        // when center <= 0, in which case center > m8 >= ... careful: must
        // include the literal 0 like the reference does.
        float4 m8 = vmax4(vmax4(h3p, h3n), h2c);
        float4 o;
        o.x = (vc.x > fmaxf(m8.x, 0.0f)) ? vc.x : 0.0f;
        o.y = (vc.y > fmaxf(m8.y, 0.0f)) ? vc.y : 0.0f;
        o.z = (vc.z > fmaxf(m8.z, 0.0f)) ? vc.z : 0.0f;
        o.w = (vc.w > fmaxf(m8.w, 0.0f)) ? vc.w : 0.0f;
        *(float4*)(oimg + (size_t)(r0 + k) * IMG_W + c0) = o;
        h3p = h3c; h2p = h2c; vp = vc;
        h3c = h3n; h2c = h2n; vc = vn;
    }
}

extern "C" void kernel_launch(void* const* d_in, const int* in_sizes, int n_in,
                              void* d_out, int out_size, void* d_ws, size_t ws_size,
                              hipStream_t stream) {
    const float* x = (const float*)d_in[0];
    float* out     = (float*)d_out;
    dim3 grid(IMG_H / (2 * RPT), 8 * 32);   // 32 row-tiles x 256 planes
    nms3x3_kernel<<<grid, dim3(THREADS), 0, stream>>>(x, out);
}